// Round 22
// baseline (297.637 us; speedup 1.0000x reference)
//
#include <hip/hip_runtime.h>
#include <hip/hip_bf16.h>
#include <stdint.h>

// ---------------------------------------------------------------------------
// Fused (base+LoRA) QKV projection -> MHA with bool mask -> out proj.
// B=8 S=1024 D=1024 H=8 DK=128 R=16.  Inputs fp32 (device-detected, bf16
// fallback).  Internal pipeline fp16.  reshape = FLAT VIEW.
// R21->R22: GEMM core -> BK=32 DOUBLE-BUFFERED prefetch: STAGE(next buf) ->
// compute(cur buf) -> __syncthreads.  The barrier's vmcnt(0) drain now
// comes AFTER the MFMA phase (overlap) instead of right after issue (full
// exposure).  LDS 2x(8+8)KB = 32KB unchanged -> 5 blocks/CU preserved;
// barrier count unchanged (1x32 vs 2x16); plain __syncthreads correctness
// (prologue drains buf0; each iter writes only the non-current buffer).
// Swizzle = R12 BK=32 pattern (measured 0 conflicts).  attn unchanged.
// ---------------------------------------------------------------------------

#define kB 8
#define kS 1024
#define kD 1024
#define kH 8
#define kDK 128
#define kHDK 1024
#define kM (kB * kS)                       // 8192
#define kMaskWords (kB * kS * (kS / 64))   // 131072 uint64 words
#define kQKVN (kM * kHDK)                  // 8388608 elements

typedef _Float16 f16;
typedef __attribute__((ext_vector_type(4))) float f32x4;
typedef __attribute__((ext_vector_type(8))) _Float16 f16x8;

// ws layout (bytes)
#define OFF_FLAG  ((size_t)0)                                   // flags[0]=mask width, flags[1]=fp32?
#define OFF_MBITS ((size_t)256)
#define OFF_WQT   (OFF_MBITS + (size_t)kMaskWords * 8)
#define OFF_WKT   (OFF_WQT + (size_t)2097152)
#define OFF_WVT   (OFF_WKT + (size_t)2097152)
#define OFF_WOT   (OFF_WVT + (size_t)2097152)
#define OFF_Q     (OFF_WOT + (size_t)2097152)
#define OFF_K     (OFF_Q  + (size_t)kQKVN * 2)
#define OFF_VT    (OFF_K  + (size_t)kQKVN * 2)
#define OFF_X     (OFF_VT + (size_t)kQKVN * 2)
#define OFF_T0    OFF_X                                  // tmp_q aliases xb
#define OFF_T1    (OFF_X + (size_t)kQKVN * 2)
#define OFF_T2    (OFF_X + (size_t)kQKVN * 4)
#define NEED3     (OFF_X + (size_t)kQKVN * 6)             // ~108 MB

__device__ __forceinline__ void async_load16(const void* g, void* lds_uniform) {
  auto gp = reinterpret_cast<const __attribute__((address_space(1))) unsigned int*>(
      reinterpret_cast<uintptr_t>(g));
  auto lp = reinterpret_cast<__attribute__((address_space(3))) unsigned int*>(
      reinterpret_cast<uintptr_t>(lds_uniform));
  __builtin_amdgcn_global_load_lds(gp, lp, 16, 0, 0);
}

__device__ __forceinline__ f32x4 mfma16(f16x8 a, f16x8 b, f32x4 c) {
  return __builtin_amdgcn_mfma_f32_16x16x32_f16(a, b, c, 0, 0, 0);
}

// flag-based scalar read of a float tensor that is fp32 (f=1) or bf16 (f=0)
__device__ __forceinline__ float ldw(const void* p, size_t i, int f) {
  return f ? ((const float*)p)[i] : (float)((const __bf16*)p)[i];
}

// XCD-chunked tile remap: XCD (L&7) gets contiguous m-tile chunk, all n.
// Requires gridDim.y % 8 == 0.
__device__ __forceinline__ void swz_tiles(int& mt, int& nt) {
  const int gx = gridDim.x, gy = gridDim.y;
  const int L = blockIdx.y * gx + blockIdx.x;
  const int xcd = L & 7, rank = L >> 3;
  mt = xcd * (gy >> 3) + rank / gx;
  nt = rank % gx;
}

// ---------------------------------------------------------------------------
// Detect (wave-parallel): flags[1]=fp32?, flags[0]=mask elem width (1/2/4 B).
// ---------------------------------------------------------------------------
__global__ void detect_kernel(const unsigned int* __restrict__ qw,
                              const unsigned int* __restrict__ mw,
                              int* __restrict__ flags) {
  const int lane = threadIdx.x & 63;
  int hi = 0; bool w4 = true, b1 = true;
  #pragma unroll
  for (int j = 0; j < 4; ++j) {
    unsigned int w = qw[lane * 4 + j];
    hi += (int)(((w >> 7) & 0xFF) > 0x90) + (int)(((w >> 23) & 0xFF) > 0x90);
    unsigned int m = mw[lane * 4 + j];
    if (!(m == 0u || m == 1u || m == 0x3F800000u)) w4 = false;
    if ((m & 0xFEFEFEFEu) != 0u) b1 = false;
  }
  #pragma unroll
  for (int off = 32; off; off >>= 1) hi += __shfl_xor(hi, off, 64);
  unsigned long long bw4 = __ballot(w4), bb1 = __ballot(b1);
  if (lane == 0 && blockIdx.x == 0) {
    flags[1] = (hi > 16) ? 1 : 0;
    flags[0] = (bw4 == ~0ull) ? 4 : ((bb1 == ~0ull) ? 1 : 2);
  }
}

// Pack mask into bit-words: word wi covers mask flat elements [wi*64, wi*64+64)
__global__ void pack_mask_kernel(const void* __restrict__ mask, const int* __restrict__ flags,
                                 unsigned long long* __restrict__ mbits) {
  int wi = blockIdx.x * 4 + (threadIdx.x >> 6);
  if (wi >= kMaskWords) return;
  int lane = threadIdx.x & 63;
  size_t e = (size_t)wi * 64 + lane;
  int width = flags[0];
  bool on;
  if (width == 1)      on = ((const unsigned char*)mask)[e] != 0;
  else if (width == 2) on = ((const unsigned short*)mask)[e] != 0;
  else                 on = ((const unsigned int*)mask)[e] != 0;
  unsigned long long bal = __ballot(on);
  if (lane == 0) mbits[wi] = bal;
}

// Convert one float tensor (fp32 or bf16 per flags[1]) to f16 dst.
__device__ __forceinline__ void convert_body(const void* src, f16* dst,
                                             const int* flags, int i) {
  f16x8 o;
  if (flags[1]) {
    f32x4 a = *(const f32x4*)((const float*)src + i);
    f32x4 b = *(const f32x4*)((const float*)src + i + 4);
    #pragma unroll
    for (int j = 0; j < 4; ++j) { o[j] = (f16)a[j]; o[4 + j] = (f16)b[j]; }
  } else {
    const __bf16* s = (const __bf16*)src + i;
    #pragma unroll
    for (int j = 0; j < 8; ++j) o[j] = (f16)(float)s[j];
  }
  *(f16x8*)(dst + i) = o;
}

__global__ __launch_bounds__(256) void convert_kernel(
    const void* __restrict__ src, f16* __restrict__ dst,
    const int* __restrict__ flags, int n) {
  const int i = (blockIdx.x * 256 + threadIdx.x) * 8;
  if (i < n) convert_body(src, dst, flags, i);
}

// z=0/1/2 -> (src,dst) pair
__global__ __launch_bounds__(256) void convert3_kernel(
    const void* __restrict__ s0, const void* __restrict__ s1, const void* __restrict__ s2,
    f16* __restrict__ d0, f16* __restrict__ d1, f16* __restrict__ d2,
    const int* __restrict__ flags) {
  const int z = blockIdx.z;
  const void* src = (z == 0) ? s0 : (z == 1) ? s1 : s2;
  f16* dst = (z == 0) ? d0 : (z == 1) ? d1 : d2;
  const int i = (blockIdx.x * 256 + threadIdx.x) * 8;
  if (i < kQKVN) convert_body(src, dst, flags, i);
}

// ---------------------------------------------------------------------------
// Effective transposed weights: WeffT[n][k] = W[k][n] + sum_r A[k][r]B[r][n]
// ---------------------------------------------------------------------------
__global__ __launch_bounds__(256) void build_weights_kernel(
    const void* __restrict__ Wq, const void* __restrict__ WA, const void* __restrict__ WB,
    const void* __restrict__ Wk, const void* __restrict__ WC, const void* __restrict__ WD,
    const void* __restrict__ Wv, const void* __restrict__ WE, const void* __restrict__ WF,
    const void* __restrict__ Wo, const int* __restrict__ flags,
    f16* __restrict__ WqT, f16* __restrict__ WkT,
    f16* __restrict__ WvT, f16* __restrict__ WoT) {
  const int z = blockIdx.z;
  const int f = flags[1];
  const void *W, *Aw = nullptr, *Bw = nullptr;
  f16* Out;
  if (z == 0)      { W = Wq; Aw = WA; Bw = WB; Out = WqT; }
  else if (z == 1) { W = Wk; Aw = WC; Bw = WD; Out = WkT; }
  else if (z == 2) { W = Wv; Aw = WE; Bw = WF; Out = WvT; }
  else             { W = Wo;                   Out = WoT; }

  __shared__ float Wt[32][33];
  __shared__ float At[32][16];
  __shared__ float Bt[16][33];
  const int tx = threadIdx.x, ty = threadIdx.y;     // block (32,8)
  const int k0 = blockIdx.y * 32, n0 = blockIdx.x * 32;
  #pragma unroll
  for (int i = 0; i < 4; ++i)
    Wt[ty + 8 * i][tx] = ldw(W, (size_t)(k0 + ty + 8 * i) * 1024 + n0 + tx, f);
  const int t = ty * 32 + tx;
  if (Aw) {
    #pragma unroll
    for (int j = 0; j < 2; ++j) {
      int e = t + j * 256;                          // 512 elems: 32x16
      At[e >> 4][e & 15] = ldw(Aw, (size_t)(k0 + (e >> 4)) * 16 + (e & 15), f);
    }
    #pragma unroll
    for (int j = 0; j < 2; ++j) {
      int e = t + j * 256;                          // 512 elems: 16x32
      Bt[e >> 5][e & 31] = ldw(Bw, (size_t)(e >> 5) * 1024 + n0 + (e & 31), f);
    }
  }
  __syncthreads();
  #pragma unroll
  for (int i = 0; i < 4; ++i) {
    const int nloc = ty + 8 * i, kloc = tx;
    float acc = Wt[kloc][nloc];
    if (Aw) {
      #pragma unroll
      for (int r = 0; r < 16; ++r) acc += At[kloc][r] * Bt[r][nloc];
    }
    Out[(size_t)(n0 + nloc) * 1024 + k0 + kloc] = (f16)acc;
  }
}

// ---------------------------------------------------------------------------
// GEMM epilogue (shared): bias add + layout-dependent store.
// ---------------------------------------------------------------------------
__device__ __forceinline__ void gemm_epilogue(
    f32x4 acc[4][4], const void* bias, void* C, int f, int vtrans, int out_dyn,
    int N, int m0, int n0, int wr, int wc, int l15, int hi) {
  const int wf32 = out_dyn && f;
  #pragma unroll
  for (int mi = 0; mi < 4; ++mi) {
    #pragma unroll
    for (int ni = 0; ni < 4; ++ni) {
      #pragma unroll
      for (int r = 0; r < 4; ++r) {
        const int row = m0 + wr * 64 + mi * 16 + 4 * hi + r;
        const int col = n0 + wc * 64 + ni * 16 + l15;
        float v = acc[mi][ni][r] + (bias ? ldw(bias, col, f) : 0.f);
        if (vtrans) {
          // scatter into V^T[b][h][d][s]: flat-view remap of (row,col)
          const int b = row >> 10, sp = row & 1023;
          const int fi = (sp << 10) | col;
          const int h = fi >> 17, s = (fi >> 7) & 1023, d = fi & 127;
          ((f16*)C)[(((size_t)(b * 8 + h) * 128 + d) << 10) + s] = (f16)v;
        } else if (wf32) {
          ((float*)C)[(size_t)row * N + col] = v;
        } else if (out_dyn) {
          ((__bf16*)C)[(size_t)row * N + col] = (__bf16)v;
        } else {
          ((f16*)C)[(size_t)row * N + col] = (f16)v;
        }
      }
    }
  }
}

// ---------------------------------------------------------------------------
// GEMM core: BK=32 DOUBLE-BUFFERED.  Per buffer: As/Bs [128][32] f16 = 8KB.
// Loop: STAGE(next into buf^1) -> compute(buf) -> __syncthreads (drain after
// the compute phase -> overlap).  Swizzle: chunk c -> c ^ ((c>>3)&3)
// (piece ^= (row>>1)&3); read at 8*(hi ^ ((l15>>1)&3)) -- R12-measured
// 0 bank conflicts.  Total LDS 32KB -> 5 blocks/CU (unchanged).
// ---------------------------------------------------------------------------
__device__ __forceinline__ void gemm_core32p(
    const f16* A, const f16* BT, const void* bias, void* C,
    int f, int vtrans, int out_dyn, int N, int K,
    int m0, int n0, f16* As, f16* Bs) {      // As,Bs: 2*4096 f16 each
  const int tid = threadIdx.x;
  const int lane = tid & 63, w = tid >> 6;
  const int wr = w >> 1, wc = w & 1;
  const int l15 = lane & 15, hi = lane >> 4;
  const int swr = (l15 >> 1) & 3;

  auto stage = [&](int sel, int k0) {
    #pragma unroll
    for (int j = 0; j < 2; ++j) {
      int c = tid + j * 256;                 // 512 chunks per operand tile
      int cs = c ^ ((c >> 3) & 3);
      int row = cs >> 2, piece = cs & 3;
      async_load16(A  + (size_t)(m0 + row) * K + k0 + piece * 8,
                   (char*)As + sel * 8192 + (w * 64 + j * 256) * 16);
      async_load16(BT + (size_t)(n0 + row) * K + k0 + piece * 8,
                   (char*)Bs + sel * 8192 + (w * 64 + j * 256) * 16);
    }
  };

  f32x4 acc[4][4];
  #pragma unroll
  for (int i = 0; i < 4; ++i)
    #pragma unroll
    for (int j = 0; j < 4; ++j) acc[i][j] = (f32x4){0.f, 0.f, 0.f, 0.f};

  stage(0, 0);
  __syncthreads();                           // buf0 landed
  int cur = 0;
  for (int k0 = 0; k0 < K; k0 += 32) {
    if (k0 + 32 < K) stage(cur ^ 1, k0 + 32);   // prefetch issue (no wait)
    const f16* Ab = As + cur * 4096;
    const f16* Bb = Bs + cur * 4096;
    f16x8 af[4], bf_[4];
    #pragma unroll
    for (int mi = 0; mi < 4; ++mi)
      af[mi] = *(const f16x8*)&Ab[(wr * 64 + mi * 16 + l15) * 32 + 8 * (hi ^ swr)];
    #pragma unroll
    for (int ni = 0; ni < 4; ++ni)
      bf_[ni] = *(const f16x8*)&Bb[(wc * 64 + ni * 16 + l15) * 32 + 8 * (hi ^ swr)];
    #pragma unroll
    for (int mi = 0; mi < 4; ++mi)
      #pragma unroll
      for (int ni = 0; ni < 4; ++ni)
        acc[mi][ni] = mfma16(af[mi], bf_[ni], acc[mi][ni]);
    __syncthreads();                         // drain prefetch (flew during MFMA)
    cur ^= 1;
  }

  gemm_epilogue(acc, bias, C, f, vtrans, out_dyn, N, m0, n0, wr, wc, l15, hi);
}

__global__ __launch_bounds__(256) void gemm_bt_kernel(
    const f16* __restrict__ A, const f16* __restrict__ BT,
    const void* __restrict__ bias, void* __restrict__ C,
    const int* __restrict__ flags, int vtrans, int out_dyn, int N, int K) {
  __shared__ __align__(16) f16 As[2 * 4096];
  __shared__ __align__(16) f16 Bs[2 * 4096];
  int mt, nt;
  swz_tiles(mt, nt);
  gemm_core32p(A, BT, bias, C, flags[1], vtrans, out_dyn, N, K,
               mt * 128, nt * 128, As, Bs);
}

// merged q/k/v projection: z selects tensors; z==2 writes V^T-scattered
__global__ __launch_bounds__(256) void gemm3_kernel(
    const f16* __restrict__ A0, const f16* __restrict__ A1, const f16* __restrict__ A2,
    const f16* __restrict__ B0, const f16* __restrict__ B1, const f16* __restrict__ B2,
    const void* __restrict__ b0, const void* __restrict__ b1, const void* __restrict__ b2,
    f16* __restrict__ C0, f16* __restrict__ C1, f16* __restrict__ C2,
    const int* __restrict__ flags) {
  __shared__ __align__(16) f16 As[2 * 4096];
  __shared__ __align__(16) f16 Bs[2 * 4096];
  const int z = blockIdx.z;
  const f16* A  = (z == 0) ? A0 : (z == 1) ? A1 : A2;
  const f16* BT = (z == 0) ? B0 : (z == 1) ? B1 : B2;
  const void* bias = (z == 0) ? b0 : (z == 1) ? b1 : b2;
  f16* C = (z == 0) ? C0 : (z == 1) ? C1 : C2;
  int mt, nt;
  swz_tiles(mt, nt);
  gemm_core32p(A, BT, bias, C, flags[1], (z == 2) ? 1 : 0, 0, 1024, 1024,
               mt * 128, nt * 128, As, Bs);
}

// ---------------------------------------------------------------------------
// Flash attention: grid (16, 64) with XCD-chunked head affinity -- XCD k
// owns heads [8k, 8k+8) (4MB K/V = its L2).  Per block: Q-tile 64 rows,
// 4 waves, KV tiles of 64.  Q in registers; LDS = Ks+Vs+Ps = 40KB.
// Softmax: __any-gated defer-max (THR=8), row-sum l via ones-MFMA,
// exp unguarded (exp(-inf-m)=0).  Swizzles: Ks chunk c -> c ^ ((c>>4)&7);
// Vs/Ps element (row,col) at row*64 + ((col>>3)^(row&7))*8 + (col&7).
// ---------------------------------------------------------------------------
__global__ __launch_bounds__(256) void attn_kernel(
    const f16* __restrict__ qbuf, const f16* __restrict__ kbuf,
    const f16* __restrict__ vT, const unsigned long long* __restrict__ mbits,
    f16* __restrict__ xbuf) {
  __shared__ __align__(16) f16 Ks[64 * 128];
  __shared__ __align__(16) f16 Vs[128 * 64];   // V^T tile: [d][kv]
  __shared__ __align__(16) f16 Ps[64 * 64];

  const int tid = threadIdx.x, lane = tid & 63, wv = tid >> 6;
  const int l15 = lane & 15, hi = lane >> 4;
  // XCD-chunked remap: L in [0,1024), xcd = L&7 -> heads [8*xcd, 8*xcd+8)
  const int L = blockIdx.y * 16 + blockIdx.x;
  const int xcd = L & 7, rank = L >> 3;
  const int head_lin = xcd * 8 + (rank >> 4);      // b*8+h
  const int q0 = (rank & 15) * 64;
  const size_t chunk = (size_t)head_lin * (kS * kDK);
  const f16* Qg = qbuf + chunk + (size_t)q0 * kDK;
  const f16* Kg = kbuf + chunk;
  const f16* Vg = vT + chunk;                      // rows d (stride kS)
  const unsigned long long* mrow = mbits + (size_t)(head_lin >> 3) * kS * 16;

  // Q A-fragments direct to registers: row (wv*16+l15), cols kk*32+8*hi..+7
  const int arow = wv * 16 + l15;
  f16x8 qf[4];
  #pragma unroll
  for (int kk = 0; kk < 4; ++kk)
    qf[kk] = *(const f16x8*)&Qg[(size_t)arow * 128 + kk * 32 + 8 * hi];

  f16x8 fone;
  #pragma unroll
  for (int j = 0; j < 8; ++j) fone[j] = (f16)1.f;

  const float NEG_INF = -__builtin_inff();
  float m_run[4] = {NEG_INF, NEG_INF, NEG_INF, NEG_INF};
  f32x4 acc_l = (f32x4){0.f, 0.f, 0.f, 0.f};       // row-sums via ones-MFMA
  f32x4 acc_o[8];
  #pragma unroll
  for (int j = 0; j < 8; ++j) acc_o[j] = (f32x4){0.f, 0.f, 0.f, 0.f};

  for (int t = 0; t < 16; ++t) {
    const int kv0 = t * 64;
    if (t) __syncthreads();
    #pragma unroll
    for (int j = 0; j < 4; ++j) {                    // K tile
      int c = tid + j * 256;
      int cs = c ^ ((c >> 4) & 7);
      async_load16((const char*)Kg + (size_t)kv0 * 256 + cs * 16,
                   (char*)Ks + (wv * 64 + j * 256) * 16);
    }
    #pragma unroll
    for (int j = 0; j < 4; ++j) {                    // V^T tile [128][64]
      int c = tid + j * 256;
      int row = c >> 3, piece = (c & 7) ^ (row & 7);
      async_load16((const char*)Vg + ((size_t)row * kS + kv0 + piece * 8) * 2,
                   (char*)Vs + (wv * 64 + j * 256) * 16);
    }
    __syncthreads();

    f32x4 accs[4];
    #pragma unroll
    for (int i = 0; i < 4; ++i) accs[i] = (f32x4){0.f, 0.f, 0.f, 0.f};
    #pragma unroll
    for (int kk = 0; kk < 4; ++kk) {
      #pragma unroll
      for (int ni = 0; ni < 4; ++ni) {
        const int brow = ni * 16 + l15;
        f16x8 bk = *(const f16x8*)&Ks[brow * 128 + (((kk * 4 + hi) ^ (brow & 7)) << 3)];
        accs[ni] = mfma16(qf[kk], bk, accs[ni]);
      }
    }

    // softmax: mask in-place, __any-gated max tree, unguarded exp
    #pragma unroll
    for (int r = 0; r < 4; ++r) {
      const int prow = wv * 16 + 4 * hi + r;
      const int qrow = q0 + prow;
      const unsigned long long mw = mrow[(size_t)qrow * 16 + t];
      #pragma unroll
      for (int ni = 0; ni < 4; ++ni) {
        const int col = ni * 16 + l15;
        const bool on = (mw >> col) & 1ull;
        accs[ni][r] = on ? accs[ni][r] : NEG_INF;
      }
      const float gmax = fmaxf(fmaxf(accs[0][r], accs[1][r]),
                               fmaxf(accs[2][r], accs[3][r]));
      const float mold = m_run[r];
      if (__any(gmax > mold + 8.f)) {                // rare after tile 0
        float tmax = gmax;
        #pragma unroll
        for (int off = 8; off; off >>= 1) tmax = fmaxf(tmax, __shfl_xor(tmax, off, 64));
        const float mnew = fmaxf(mold, tmax);
        if (mnew > mold) {                           // row-uniform within hi-group
          const float alpha = __expf(mold - mnew);   // exp(-inf)=0 on first tile
          #pragma unroll
          for (int nj = 0; nj < 8; ++nj) acc_o[nj][r] *= alpha;
          acc_l[r] *= alpha;
          m_run[r] = mnew;
        }
      }
      const float m = m_run[r];
      #pragma unroll
      for (int ni = 0; ni < 4; ++ni) {
        const float p = __expf(accs[ni][r] - m);     // -inf - m -> exp = 0
        const int col = ni * 16 + l15;
        Ps[prow * 64 + (((col >> 3) ^ (prow & 7)) << 3) + (col & 7)] = (f16)p;
      }
    }

    const int prow2 = wv * 16 + l15;
    #pragma unroll
    for (int kk = 0; kk < 2; ++kk) {
      f16x8 ap = *(const f16x8*)&Ps[prow2 * 64 + (((kk * 4 + hi) ^ (prow2 & 7)) << 3)];
      acc_l = mfma16(ap, fone, acc_l);               // l += row-sum(P)
      #pragma unroll
      for (int nj = 0; nj < 8; ++nj) {
        const int vrow = nj * 16 + l15;
        f16x8 bv = *(const f16x8*)&Vs[vrow * 64 + (((kk * 4 + hi) ^ (vrow & 7)) << 3)];
        acc_o[nj] = mfma16(ap, bv, acc_o[nj]);
      }
    }
  }

  #pragma unroll
  for (int r = 0; r < 4; ++r) {
    const float inv = (acc_l[r] > 0.f) ? 1.f / acc_l[r] : 0.f;
    const int row = q0 + wv * 16 + 4 * hi + r;
    #pragma unroll
    for (int nj = 0; nj < 8; ++nj)
      xbuf[chunk + (size_t)row * kDK + nj * 16 + l15] = (f16)(acc_o[nj][r] * inv);
  }
}

// ---------------------------------------------------------------------------
extern "C" void kernel_launch(void* const* d_in, const int* in_sizes, int n_in,
                              void* d_out, int out_size, void* d_ws, size_t ws_size,
                              hipStream_t stream) {
  const void* query = d_in[0];
  const void* key_  = d_in[1];
  const void* value = d_in[2];
  const void* mask  = d_in[3];
  const void* W_A = d_in[4];
  const void* W_B = d_in[5];
  const void* W_C = d_in[6];
  const void* W_D = d_in[7];
  const void* W_E = d_in[8];
  const void* W_F = d_in[9];
  const void* Wq  = d_in[10];
  const void* bq  = d_in[11];
  const void* Wk  = d_in[12];
  const void* bk  = d_in[13];
  const void* Wv  = d_in[14];
  const void* bv  = d_in[15];
  const void* Wo  = d_in[16];
  const void* bo  = d_in[17];

  char* ws = (char*)d_ws;
  int* flags = (int*)(ws + OFF_FLAG);
  unsigned long long* mbits = (unsigned long long*)(ws + OFF_MBITS);
  f16* WqT = (f16*)(ws + OFF_WQT);
  f16* WkT = (f16*)(ws + OFF_WKT);
  f16* WvT = (f16*)(ws + OFF_WVT);
  f16* WoT = (f16*)(ws + OFF_WOT);
  f16* qb  = (f16*)(ws + OFF_Q);
  f16* kb  = (f16*)(ws + OFF_K);
  f16* vTb = (f16*)(ws + OFF_VT);
  f16* xb  = (f16*)(ws + OFF_X);

  detect_kernel<<<1, 64, 0, stream>>>((const unsigned int*)query,
                                      (const unsigned int*)mask, flags);
  pack_mask_kernel<<<kMaskWords / 4, 256, 0, stream>>>(mask, flags, mbits);
  build_weights_kernel<<<dim3(32, 32, 4), dim3(32, 8), 0, stream>>>(
      Wq, W_A, W_B, Wk, W_C, W_D, Wv, W_E, W_F, Wo, flags, WqT, WkT, WvT, WoT);

  if (ws_size >= NEED3) {
    // merged path: 3 staging buffers -> one z=3 projection launch
    f16* t0 = (f16*)(ws + OFF_T0);
    f16* t1 = (f16*)(ws + OFF_T1);
    f16* t2 = (f16*)(ws + OFF_T2);
    convert3_kernel<<<dim3(kQKVN / (256 * 8), 1, 3), 256, 0, stream>>>(
        query, key_, value, t0, t1, t2, flags);
    gemm3_kernel<<<dim3(8, 64, 3), 256, 0, stream>>>(
        t0, t1, t2, WqT, WkT, WvT, bq, bk, bv, qb, kb, vTb, flags);
  } else {
    // sequential fallback (tmp aliases xb; dead before attn)
    f16* tmp = (f16*)(ws + OFF_X);
    convert_kernel<<<kQKVN / (256 * 8), 256, 0, stream>>>(query, tmp, flags, kQKVN);
    gemm_bt_kernel<<<dim3(8, 64), 256, 0, stream>>>(
        tmp, WqT, bq, qb, flags, 0, 0, kHDK, kD);
    convert_kernel<<<kQKVN / (256 * 8), 256, 0, stream>>>(key_, tmp, flags, kQKVN);
    gemm_bt_kernel<<<dim3(8, 64), 256, 0, stream>>>(
        tmp, WkT, bk, kb, flags, 0, 0, kHDK, kD);
    convert_kernel<<<kQKVN / (256 * 8), 256, 0, stream>>>(value, tmp, flags, kQKVN);
    gemm_bt_kernel<<<dim3(8, 64), 256, 0, stream>>>(
        tmp, WvT, bv, vTb, flags, 1, 0, kHDK, kD);
  }

  attn_kernel<<<dim3(16, 64), 256, 0, stream>>>(qb, kb, vTb, mbits, xb);

  // out-projection: N = kD (1024), K = kHDK (1024)
  gemm_bt_kernel<<<dim3(8, 64), 256, 0, stream>>>(
      xb, WoT, bo, d_out, flags, 0, /*out_dyn=*/1, kD, kHDK);
}

// Round 23
// 284.346 us; speedup vs baseline: 1.0467x; 1.0467x over previous
//
#include <hip/hip_runtime.h>
#include <hip/hip_bf16.h>
#include <stdint.h>

// ---------------------------------------------------------------------------
// FINAL (R23 = R21, best measured 286.1us).  Fused (base+LoRA) QKV
// projection -> MHA with bool mask -> out proj.  B=8 S=1024 D=1024 H=8
// DK=128 R=16.  Inputs fp32 (device-detected, bf16 fallback).  Internal
// pipeline fp16 (bf16 fails absmax: scores sigma~11, no 1/sqrt(dk)).
// reshape(nb,H,-1,DK) is a FLAT VIEW: head = contiguous chunk.
// R22's explicit double-buffer regressed (107->120us; replicates guide
// m99-m141: source-level pipelining can't beat the vmcnt-drain barrier;
// inter-block TLP at 5 blk/CU already covers the latency).  Reverted.
// Validated levers in this build: LoRA folded into effective weights;
// V^T written by projection epilogue; T2 LDS XOR-swizzles (0 conflicts);
// T1 XCD-chunked swizzles (GEMM m-panels; attn head affinity); BK=64;
// merged convert3/gemm3 launches; attn: Q-in-registers, MFMA row-sum,
// __any-gated defer-max, unguarded exp.
// ---------------------------------------------------------------------------

#define kB 8
#define kS 1024
#define kD 1024
#define kH 8
#define kDK 128
#define kHDK 1024
#define kM (kB * kS)                       // 8192
#define kMaskWords (kB * kS * (kS / 64))   // 131072 uint64 words
#define kQKVN (kM * kHDK)                  // 8388608 elements

typedef _Float16 f16;
typedef __attribute__((ext_vector_type(4))) float f32x4;
typedef __attribute__((ext_vector_type(8))) _Float16 f16x8;

// ws layout (bytes)
#define OFF_FLAG  ((size_t)0)                                   // flags[0]=mask width, flags[1]=fp32?
#define OFF_MBITS ((size_t)256)
#define OFF_WQT   (OFF_MBITS + (size_t)kMaskWords * 8)
#define OFF_WKT   (OFF_WQT + (size_t)2097152)
#define OFF_WVT   (OFF_WKT + (size_t)2097152)
#define OFF_WOT   (OFF_WVT + (size_t)2097152)
#define OFF_Q     (OFF_WOT + (size_t)2097152)
#define OFF_K     (OFF_Q  + (size_t)kQKVN * 2)
#define OFF_VT    (OFF_K  + (size_t)kQKVN * 2)
#define OFF_X     (OFF_VT + (size_t)kQKVN * 2)
#define OFF_T0    OFF_X                                  // tmp_q aliases xb
#define OFF_T1    (OFF_X + (size_t)kQKVN * 2)
#define OFF_T2    (OFF_X + (size_t)kQKVN * 4)
#define NEED3     (OFF_X + (size_t)kQKVN * 6)             // ~108 MB

__device__ __forceinline__ void async_load16(const void* g, void* lds_uniform) {
  auto gp = reinterpret_cast<const __attribute__((address_space(1))) unsigned int*>(
      reinterpret_cast<uintptr_t>(g));
  auto lp = reinterpret_cast<__attribute__((address_space(3))) unsigned int*>(
      reinterpret_cast<uintptr_t>(lds_uniform));
  __builtin_amdgcn_global_load_lds(gp, lp, 16, 0, 0);
}

__device__ __forceinline__ f32x4 mfma16(f16x8 a, f16x8 b, f32x4 c) {
  return __builtin_amdgcn_mfma_f32_16x16x32_f16(a, b, c, 0, 0, 0);
}

// flag-based scalar read of a float tensor that is fp32 (f=1) or bf16 (f=0)
__device__ __forceinline__ float ldw(const void* p, size_t i, int f) {
  return f ? ((const float*)p)[i] : (float)((const __bf16*)p)[i];
}

// XCD-chunked tile remap: XCD (L&7) gets contiguous m-tile chunk, all n.
// Requires gridDim.y % 8 == 0.
__device__ __forceinline__ void swz_tiles(int& mt, int& nt) {
  const int gx = gridDim.x, gy = gridDim.y;
  const int L = blockIdx.y * gx + blockIdx.x;
  const int xcd = L & 7, rank = L >> 3;
  mt = xcd * (gy >> 3) + rank / gx;
  nt = rank % gx;
}

// ---------------------------------------------------------------------------
// Detect (wave-parallel): flags[1]=fp32?, flags[0]=mask elem width (1/2/4 B).
// ---------------------------------------------------------------------------
__global__ void detect_kernel(const unsigned int* __restrict__ qw,
                              const unsigned int* __restrict__ mw,
                              int* __restrict__ flags) {
  const int lane = threadIdx.x & 63;
  int hi = 0; bool w4 = true, b1 = true;
  #pragma unroll
  for (int j = 0; j < 4; ++j) {
    unsigned int w = qw[lane * 4 + j];
    hi += (int)(((w >> 7) & 0xFF) > 0x90) + (int)(((w >> 23) & 0xFF) > 0x90);
    unsigned int m = mw[lane * 4 + j];
    if (!(m == 0u || m == 1u || m == 0x3F800000u)) w4 = false;
    if ((m & 0xFEFEFEFEu) != 0u) b1 = false;
  }
  #pragma unroll
  for (int off = 32; off; off >>= 1) hi += __shfl_xor(hi, off, 64);
  unsigned long long bw4 = __ballot(w4), bb1 = __ballot(b1);
  if (lane == 0 && blockIdx.x == 0) {
    flags[1] = (hi > 16) ? 1 : 0;
    flags[0] = (bw4 == ~0ull) ? 4 : ((bb1 == ~0ull) ? 1 : 2);
  }
}

// Pack mask into bit-words: word wi covers mask flat elements [wi*64, wi*64+64)
__global__ void pack_mask_kernel(const void* __restrict__ mask, const int* __restrict__ flags,
                                 unsigned long long* __restrict__ mbits) {
  int wi = blockIdx.x * 4 + (threadIdx.x >> 6);
  if (wi >= kMaskWords) return;
  int lane = threadIdx.x & 63;
  size_t e = (size_t)wi * 64 + lane;
  int width = flags[0];
  bool on;
  if (width == 1)      on = ((const unsigned char*)mask)[e] != 0;
  else if (width == 2) on = ((const unsigned short*)mask)[e] != 0;
  else                 on = ((const unsigned int*)mask)[e] != 0;
  unsigned long long bal = __ballot(on);
  if (lane == 0) mbits[wi] = bal;
}

// Convert one float tensor (fp32 or bf16 per flags[1]) to f16 dst.
__device__ __forceinline__ void convert_body(const void* src, f16* dst,
                                             const int* flags, int i) {
  f16x8 o;
  if (flags[1]) {
    f32x4 a = *(const f32x4*)((const float*)src + i);
    f32x4 b = *(const f32x4*)((const float*)src + i + 4);
    #pragma unroll
    for (int j = 0; j < 4; ++j) { o[j] = (f16)a[j]; o[4 + j] = (f16)b[j]; }
  } else {
    const __bf16* s = (const __bf16*)src + i;
    #pragma unroll
    for (int j = 0; j < 8; ++j) o[j] = (f16)(float)s[j];
  }
  *(f16x8*)(dst + i) = o;
}

__global__ __launch_bounds__(256) void convert_kernel(
    const void* __restrict__ src, f16* __restrict__ dst,
    const int* __restrict__ flags, int n) {
  const int i = (blockIdx.x * 256 + threadIdx.x) * 8;
  if (i < n) convert_body(src, dst, flags, i);
}

// z=0/1/2 -> (src,dst) pair
__global__ __launch_bounds__(256) void convert3_kernel(
    const void* __restrict__ s0, const void* __restrict__ s1, const void* __restrict__ s2,
    f16* __restrict__ d0, f16* __restrict__ d1, f16* __restrict__ d2,
    const int* __restrict__ flags) {
  const int z = blockIdx.z;
  const void* src = (z == 0) ? s0 : (z == 1) ? s1 : s2;
  f16* dst = (z == 0) ? d0 : (z == 1) ? d1 : d2;
  const int i = (blockIdx.x * 256 + threadIdx.x) * 8;
  if (i < kQKVN) convert_body(src, dst, flags, i);
}

// ---------------------------------------------------------------------------
// Effective transposed weights: WeffT[n][k] = W[k][n] + sum_r A[k][r]B[r][n]
// ---------------------------------------------------------------------------
__global__ __launch_bounds__(256) void build_weights_kernel(
    const void* __restrict__ Wq, const void* __restrict__ WA, const void* __restrict__ WB,
    const void* __restrict__ Wk, const void* __restrict__ WC, const void* __restrict__ WD,
    const void* __restrict__ Wv, const void* __restrict__ WE, const void* __restrict__ WF,
    const void* __restrict__ Wo, const int* __restrict__ flags,
    f16* __restrict__ WqT, f16* __restrict__ WkT,
    f16* __restrict__ WvT, f16* __restrict__ WoT) {
  const int z = blockIdx.z;
  const int f = flags[1];
  const void *W, *Aw = nullptr, *Bw = nullptr;
  f16* Out;
  if (z == 0)      { W = Wq; Aw = WA; Bw = WB; Out = WqT; }
  else if (z == 1) { W = Wk; Aw = WC; Bw = WD; Out = WkT; }
  else if (z == 2) { W = Wv; Aw = WE; Bw = WF; Out = WvT; }
  else             { W = Wo;                   Out = WoT; }

  __shared__ float Wt[32][33];
  __shared__ float At[32][16];
  __shared__ float Bt[16][33];
  const int tx = threadIdx.x, ty = threadIdx.y;     // block (32,8)
  const int k0 = blockIdx.y * 32, n0 = blockIdx.x * 32;
  #pragma unroll
  for (int i = 0; i < 4; ++i)
    Wt[ty + 8 * i][tx] = ldw(W, (size_t)(k0 + ty + 8 * i) * 1024 + n0 + tx, f);
  const int t = ty * 32 + tx;
  if (Aw) {
    #pragma unroll
    for (int j = 0; j < 2; ++j) {
      int e = t + j * 256;                          // 512 elems: 32x16
      At[e >> 4][e & 15] = ldw(Aw, (size_t)(k0 + (e >> 4)) * 16 + (e & 15), f);
    }
    #pragma unroll
    for (int j = 0; j < 2; ++j) {
      int e = t + j * 256;                          // 512 elems: 16x32
      Bt[e >> 5][e & 31] = ldw(Bw, (size_t)(e >> 5) * 1024 + n0 + (e & 31), f);
    }
  }
  __syncthreads();
  #pragma unroll
  for (int i = 0; i < 4; ++i) {
    const int nloc = ty + 8 * i, kloc = tx;
    float acc = Wt[kloc][nloc];
    if (Aw) {
      #pragma unroll
      for (int r = 0; r < 16; ++r) acc += At[kloc][r] * Bt[r][nloc];
    }
    Out[(size_t)(n0 + nloc) * 1024 + k0 + kloc] = (f16)acc;
  }
}

// ---------------------------------------------------------------------------
// GEMM epilogue (shared): bias add + layout-dependent store.
// ---------------------------------------------------------------------------
__device__ __forceinline__ void gemm_epilogue(
    f32x4 acc[4][4], const void* bias, void* C, int f, int vtrans, int out_dyn,
    int N, int m0, int n0, int wr, int wc, int l15, int hi) {
  const int wf32 = out_dyn && f;
  #pragma unroll
  for (int mi = 0; mi < 4; ++mi) {
    #pragma unroll
    for (int ni = 0; ni < 4; ++ni) {
      #pragma unroll
      for (int r = 0; r < 4; ++r) {
        const int row = m0 + wr * 64 + mi * 16 + 4 * hi + r;
        const int col = n0 + wc * 64 + ni * 16 + l15;
        float v = acc[mi][ni][r] + (bias ? ldw(bias, col, f) : 0.f);
        if (vtrans) {
          // scatter into V^T[b][h][d][s]: flat-view remap of (row,col)
          const int b = row >> 10, sp = row & 1023;
          const int fi = (sp << 10) | col;
          const int h = fi >> 17, s = (fi >> 7) & 1023, d = fi & 127;
          ((f16*)C)[(((size_t)(b * 8 + h) * 128 + d) << 10) + s] = (f16)v;
        } else if (wf32) {
          ((float*)C)[(size_t)row * N + col] = v;
        } else if (out_dyn) {
          ((__bf16*)C)[(size_t)row * N + col] = (__bf16)v;
        } else {
          ((f16*)C)[(size_t)row * N + col] = (f16)v;
        }
      }
    }
  }
}

// ---------------------------------------------------------------------------
// GEMM core: BK=64, both operands f16 via global_load_lds (hw async queue).
// LDS [128][64] f16; stored piece = logical ^ (row&7); read (4kk+hi)^(row&7).
// ---------------------------------------------------------------------------
__device__ __forceinline__ void gemm_core64(
    const f16* A, const f16* BT, const void* bias, void* C,
    int f, int vtrans, int out_dyn, int N, int K,
    int m0, int n0, f16* As, f16* Bs) {
  const int tid = threadIdx.x;
  const int lane = tid & 63, w = tid >> 6;
  const int wr = w >> 1, wc = w & 1;
  const int l15 = lane & 15, hi = lane >> 4;

  f32x4 acc[4][4];
  #pragma unroll
  for (int i = 0; i < 4; ++i)
    #pragma unroll
    for (int j = 0; j < 4; ++j) acc[i][j] = (f32x4){0.f, 0.f, 0.f, 0.f};

  for (int k0 = 0; k0 < K; k0 += 64) {
    if (k0) __syncthreads();
    #pragma unroll
    for (int j = 0; j < 4; ++j) {
      int d = tid + j * 256;                     // dest chunk (1024 per tile)
      int row = d >> 3, piece = (d & 7) ^ (row & 7);
      async_load16(A  + (size_t)(m0 + row) * K + k0 + piece * 8,
                   (char*)As + (w * 64 + j * 256) * 16);
      async_load16(BT + (size_t)(n0 + row) * K + k0 + piece * 8,
                   (char*)Bs + (w * 64 + j * 256) * 16);
    }
    __syncthreads();

    #pragma unroll
    for (int kk = 0; kk < 2; ++kk) {
      f16x8 af[4], bf_[4];
      #pragma unroll
      for (int mi = 0; mi < 4; ++mi) {
        const int row = wr * 64 + mi * 16 + l15;
        af[mi] = *(const f16x8*)&As[row * 64 + (((kk * 4 + hi) ^ (row & 7)) << 3)];
      }
      #pragma unroll
      for (int ni = 0; ni < 4; ++ni) {
        const int row = wc * 64 + ni * 16 + l15;
        bf_[ni] = *(const f16x8*)&Bs[row * 64 + (((kk * 4 + hi) ^ (row & 7)) << 3)];
      }
      #pragma unroll
      for (int mi = 0; mi < 4; ++mi)
        #pragma unroll
        for (int ni = 0; ni < 4; ++ni)
          acc[mi][ni] = mfma16(af[mi], bf_[ni], acc[mi][ni]);
    }
  }

  gemm_epilogue(acc, bias, C, f, vtrans, out_dyn, N, m0, n0, wr, wc, l15, hi);
}

__global__ __launch_bounds__(256) void gemm_bt_kernel(
    const f16* __restrict__ A, const f16* __restrict__ BT,
    const void* __restrict__ bias, void* __restrict__ C,
    const int* __restrict__ flags, int vtrans, int out_dyn, int N, int K) {
  __shared__ __align__(16) f16 As[128 * 64];
  __shared__ __align__(16) f16 Bs[128 * 64];
  int mt, nt;
  swz_tiles(mt, nt);
  gemm_core64(A, BT, bias, C, flags[1], vtrans, out_dyn, N, K,
              mt * 128, nt * 128, As, Bs);
}

// merged q/k/v projection: z selects tensors; z==2 writes V^T-scattered
__global__ __launch_bounds__(256) void gemm3_kernel(
    const f16* __restrict__ A0, const f16* __restrict__ A1, const f16* __restrict__ A2,
    const f16* __restrict__ B0, const f16* __restrict__ B1, const f16* __restrict__ B2,
    const void* __restrict__ b0, const void* __restrict__ b1, const void* __restrict__ b2,
    f16* __restrict__ C0, f16* __restrict__ C1, f16* __restrict__ C2,
    const int* __restrict__ flags) {
  __shared__ __align__(16) f16 As[128 * 64];
  __shared__ __align__(16) f16 Bs[128 * 64];
  const int z = blockIdx.z;
  const f16* A  = (z == 0) ? A0 : (z == 1) ? A1 : A2;
  const f16* BT = (z == 0) ? B0 : (z == 1) ? B1 : B2;
  const void* bias = (z == 0) ? b0 : (z == 1) ? b1 : b2;
  f16* C = (z == 0) ? C0 : (z == 1) ? C1 : C2;
  int mt, nt;
  swz_tiles(mt, nt);
  gemm_core64(A, BT, bias, C, flags[1], (z == 2) ? 1 : 0, 0, 1024, 1024,
              mt * 128, nt * 128, As, Bs);
}

// ---------------------------------------------------------------------------
// Flash attention: grid (16, 64) with XCD-chunked head affinity -- XCD k
// owns heads [8k, 8k+8) (4MB K/V = its L2).  Per block: Q-tile 64 rows,
// 4 waves, KV tiles of 64.  Q in registers; LDS = Ks+Vs+Ps = 40KB.
// Softmax: __any-gated defer-max (THR=8), row-sum l via ones-MFMA,
// exp unguarded (exp(-inf-m)=0).  Swizzles: Ks chunk c -> c ^ ((c>>4)&7);
// Vs/Ps element (row,col) at row*64 + ((col>>3)^(row&7))*8 + (col&7).
// ---------------------------------------------------------------------------
__global__ __launch_bounds__(256) void attn_kernel(
    const f16* __restrict__ qbuf, const f16* __restrict__ kbuf,
    const f16* __restrict__ vT, const unsigned long long* __restrict__ mbits,
    f16* __restrict__ xbuf) {
  __shared__ __align__(16) f16 Ks[64 * 128];
  __shared__ __align__(16) f16 Vs[128 * 64];   // V^T tile: [d][kv]
  __shared__ __align__(16) f16 Ps[64 * 64];

  const int tid = threadIdx.x, lane = tid & 63, wv = tid >> 6;
  const int l15 = lane & 15, hi = lane >> 4;
  // XCD-chunked remap: L in [0,1024), xcd = L&7 -> heads [8*xcd, 8*xcd+8)
  const int L = blockIdx.y * 16 + blockIdx.x;
  const int xcd = L & 7, rank = L >> 3;
  const int head_lin = xcd * 8 + (rank >> 4);      // b*8+h
  const int q0 = (rank & 15) * 64;
  const size_t chunk = (size_t)head_lin * (kS * kDK);
  const f16* Qg = qbuf + chunk + (size_t)q0 * kDK;
  const f16* Kg = kbuf + chunk;
  const f16* Vg = vT + chunk;                      // rows d (stride kS)
  const unsigned long long* mrow = mbits + (size_t)(head_lin >> 3) * kS * 16;

  // Q A-fragments direct to registers: row (wv*16+l15), cols kk*32+8*hi..+7
  const int arow = wv * 16 + l15;
  f16x8 qf[4];
  #pragma unroll
  for (int kk = 0; kk < 4; ++kk)
    qf[kk] = *(const f16x8*)&Qg[(size_t)arow * 128 + kk * 32 + 8 * hi];

  f16x8 fone;
  #pragma unroll
  for (int j = 0; j < 8; ++j) fone[j] = (f16)1.f;

  const float NEG_INF = -__builtin_inff();
  float m_run[4] = {NEG_INF, NEG_INF, NEG_INF, NEG_INF};
  f32x4 acc_l = (f32x4){0.f, 0.f, 0.f, 0.f};       // row-sums via ones-MFMA
  f32x4 acc_o[8];
  #pragma unroll
  for (int j = 0; j < 8; ++j) acc_o[j] = (f32x4){0.f, 0.f, 0.f, 0.f};

  for (int t = 0; t < 16; ++t) {
    const int kv0 = t * 64;
    if (t) __syncthreads();
    #pragma unroll
    for (int j = 0; j < 4; ++j) {                    // K tile
      int c = tid + j * 256;
      int cs = c ^ ((c >> 4) & 7);
      async_load16((const char*)Kg + (size_t)kv0 * 256 + cs * 16,
                   (char*)Ks + (wv * 64 + j * 256) * 16);
    }
    #pragma unroll
    for (int j = 0; j < 4; ++j) {                    // V^T tile [128][64]
      int c = tid + j * 256;
      int row = c >> 3, piece = (c & 7) ^ (row & 7);
      async_load16((const char*)Vg + ((size_t)row * kS + kv0 + piece * 8) * 2,
                   (char*)Vs + (wv * 64 + j * 256) * 16);
    }
    __syncthreads();

    f32x4 accs[4];
    #pragma unroll
    for (int i = 0; i < 4; ++i) accs[i] = (f32x4){0.f, 0.f, 0.f, 0.f};
    #pragma unroll
    for (int kk = 0; kk < 4; ++kk) {
      #pragma unroll
      for (int ni = 0; ni < 4; ++ni) {
        const int brow = ni * 16 + l15;
        f16x8 bk = *(const f16x8*)&Ks[brow * 128 + (((kk * 4 + hi) ^ (brow & 7)) << 3)];
        accs[ni] = mfma16(qf[kk], bk, accs[ni]);
      }
    }

    // softmax: mask in-place, __any-gated max tree, unguarded exp
    #pragma unroll
    for (int r = 0; r < 4; ++r) {
      const int prow = wv * 16 + 4 * hi + r;
      const int qrow = q0 + prow;
      const unsigned long long mw = mrow[(size_t)qrow * 16 + t];
      #pragma unroll
      for (int ni = 0; ni < 4; ++ni) {
        const int col = ni * 16 + l15;
        const bool on = (mw >> col) & 1ull;
        accs[ni][r] = on ? accs[ni][r] : NEG_INF;
      }
      const float gmax = fmaxf(fmaxf(accs[0][r], accs[1][r]),
                               fmaxf(accs[2][r], accs[3][r]));
      const float mold = m_run[r];
      if (__any(gmax > mold + 8.f)) {                // rare after tile 0
        float tmax = gmax;
        #pragma unroll
        for (int off = 8; off; off >>= 1) tmax = fmaxf(tmax, __shfl_xor(tmax, off, 64));
        const float mnew = fmaxf(mold, tmax);
        if (mnew > mold) {                           // row-uniform within hi-group
          const float alpha = __expf(mold - mnew);   // exp(-inf)=0 on first tile
          #pragma unroll
          for (int nj = 0; nj < 8; ++nj) acc_o[nj][r] *= alpha;
          acc_l[r] *= alpha;
          m_run[r] = mnew;
        }
      }
      const float m = m_run[r];
      #pragma unroll
      for (int ni = 0; ni < 4; ++ni) {
        const float p = __expf(accs[ni][r] - m);     // -inf - m -> exp = 0
        const int col = ni * 16 + l15;
        Ps[prow * 64 + (((col >> 3) ^ (prow & 7)) << 3) + (col & 7)] = (f16)p;
      }
    }

    const int prow2 = wv * 16 + l15;
    #pragma unroll
    for (int kk = 0; kk < 2; ++kk) {
      f16x8 ap = *(const f16x8*)&Ps[prow2 * 64 + (((kk * 4 + hi) ^ (prow2 & 7)) << 3)];
      acc_l = mfma16(ap, fone, acc_l);               // l += row-sum(P)
      #pragma unroll
      for (int nj = 0; nj < 8; ++nj) {
        const int vrow = nj * 16 + l15;
        f16x8 bv = *(const f16x8*)&Vs[vrow * 64 + (((kk * 4 + hi) ^ (vrow & 7)) << 3)];
        acc_o[nj] = mfma16(ap, bv, acc_o[nj]);
      }
    }
  }

  #pragma unroll
  for (int r = 0; r < 4; ++r) {
    const float inv = (acc_l[r] > 0.f) ? 1.f / acc_l[r] : 0.f;
    const int row = q0 + wv * 16 + 4 * hi + r;
    #pragma unroll
    for (int nj = 0; nj < 8; ++nj)
      xbuf[chunk + (size_t)row * kDK + nj * 16 + l15] = (f16)(acc_o[nj][r] * inv);
  }
}

// ---------------------------------------------------------------------------
extern "C" void kernel_launch(void* const* d_in, const int* in_sizes, int n_in,
                              void* d_out, int out_size, void* d_ws, size_t ws_size,
                              hipStream_t stream) {
  const void* query = d_in[0];
  const void* key_  = d_in[1];
  const void* value = d_in[2];
  const void* mask  = d_in[3];
  const void* W_A = d_in[4];
  const void* W_B = d_in[5];
  const void* W_C = d_in[6];
  const void* W_D = d_in[7];
  const void* W_E = d_in[8];
  const void* W_F = d_in[9];
  const void* Wq  = d_in[10];
  const void* bq  = d_in[11];
  const void* Wk  = d_in[12];
  const void* bk  = d_in[13];
  const void* Wv  = d_in[14];
  const void* bv  = d_in[15];
  const void* Wo  = d_in[16];
  const void* bo  = d_in[17];

  char* ws = (char*)d_ws;
  int* flags = (int*)(ws + OFF_FLAG);
  unsigned long long* mbits = (unsigned long long*)(ws + OFF_MBITS);
  f16* WqT = (f16*)(ws + OFF_WQT);
  f16* WkT = (f16*)(ws + OFF_WKT);
  f16* WvT = (f16*)(ws + OFF_WVT);
  f16* WoT = (f16*)(ws + OFF_WOT);
  f16* qb  = (f16*)(ws + OFF_Q);
  f16* kb  = (f16*)(ws + OFF_K);
  f16* vTb = (f16*)(ws + OFF_VT);
  f16* xb  = (f16*)(ws + OFF_X);

  detect_kernel<<<1, 64, 0, stream>>>((const unsigned int*)query,
                                      (const unsigned int*)mask, flags);
  pack_mask_kernel<<<kMaskWords / 4, 256, 0, stream>>>(mask, flags, mbits);
  build_weights_kernel<<<dim3(32, 32, 4), dim3(32, 8), 0, stream>>>(
      Wq, W_A, W_B, Wk, W_C, W_D, Wv, W_E, W_F, Wo, flags, WqT, WkT, WvT, WoT);

  if (ws_size >= NEED3) {
    // merged path: 3 staging buffers -> one z=3 projection launch
    f16* t0 = (f16*)(ws + OFF_T0);
    f16* t1 = (f16*)(ws + OFF_T1);
    f16* t2 = (f16*)(ws + OFF_T2);
    convert3_kernel<<<dim3(kQKVN / (256 * 8), 1, 3), 256, 0, stream>>>(
        query, key_, value, t0, t1, t2, flags);
    gemm3_kernel<<<dim3(8, 64, 3), 256, 0, stream>>>(
        t0, t1, t2, WqT, WkT, WvT, bq, bk, bv, qb, kb, vTb, flags);
  } else {
    // sequential fallback (tmp aliases xb; dead before attn)
    f16* tmp = (f16*)(ws + OFF_X);
    convert_kernel<<<kQKVN / (256 * 8), 256, 0, stream>>>(query, tmp, flags, kQKVN);
    gemm_bt_kernel<<<dim3(8, 64), 256, 0, stream>>>(
        tmp, WqT, bq, qb, flags, 0, 0, kHDK, kD);
    convert_kernel<<<kQKVN / (256 * 8), 256, 0, stream>>>(key_, tmp, flags, kQKVN);
    gemm_bt_kernel<<<dim3(8, 64), 256, 0, stream>>>(
        tmp, WkT, bk, kb, flags, 0, 0, kHDK, kD);
    convert_kernel<<<kQKVN / (256 * 8), 256, 0, stream>>>(value, tmp, flags, kQKVN);
    gemm_bt_kernel<<<dim3(8, 64), 256, 0, stream>>>(
        tmp, WvT, bv, vTb, flags, 1, 0, kHDK, kD);
  }

  attn_kernel<<<dim3(16, 64), 256, 0, stream>>>(qb, kb, vTb, mbits, xb);

  // out-projection: N = kD (1024), K = kHDK (1024)
  gemm_bt_kernel<<<dim3(8, 64), 256, 0, stream>>>(
      xb, WoT, bo, d_out, flags, 0, /*out_dyn=*/1, kD, kHDK);
}